// Round 10
// baseline (152.904 us; speedup 1.0000x reference)
//
#include <hip/hip_runtime.h>
#include <math.h>

// Sizes from the reference
#define B_SZ 4096
#define N_SZ 16
#define A_SZ 8
#define IN_DIM 128
#define OUT_DIM 128
#define D_OBS 128
#define ROW_OUT 136              // floats per output row = 34 float4

typedef float f32x4 __attribute__((ext_vector_type(4)));

// ws layout (floats): v[256] | asrc[B*16] | adst[B*16] | sumz[B*16*8]
#define WS_V      0
#define WS_ASRC   256
#define WS_ADST   (256 + B_SZ * 16)
#define WS_SUMZ   (256 + B_SZ * 32)
#define WS_FLOATS (256 + B_SZ * 32 + B_SZ * 128)   // 655,616 floats = 2.62 MB

// ---------------------------------------------------------------------------
// Kernel 1: fold W_attn into W_fc. v_src[i]=sum_o W_fc[o,i]*W_attn[o], etc.
// ---------------------------------------------------------------------------
__global__ __launch_bounds__(1024) void prep_v(const float* __restrict__ W_fc,
                                               const float* __restrict__ W_attn,
                                               float* __restrict__ v) {
  __shared__ float part[8][2][128];
  const int i = threadIdx.x & 127;
  const int seg = threadIdx.x >> 7;
  float s = 0.f, d = 0.f;
  #pragma unroll
  for (int oo = 0; oo < 16; ++oo) {
    const int o = seg * 16 + oo;
    const float w = W_fc[o * IN_DIM + i];
    s += w * W_attn[o];
    d += w * W_attn[OUT_DIM + o];
  }
  part[seg][0][i] = s;
  part[seg][1][i] = d;
  __syncthreads();
  if (seg == 0) {
    float ss = 0.f, dd = 0.f;
    #pragma unroll
    for (int t = 0; t < 8; ++t) { ss += part[t][0][i]; dd += part[t][1][i]; }
    v[i] = ss;
    v[IN_DIM + i] = dd;
  }
}

// ---------------------------------------------------------------------------
// Kernel 2a (new path): compute-only. Writes a_src/a_dst/sum_z to ws + out_w.
// ---------------------------------------------------------------------------
__global__ __launch_bounds__(256) void gat_compute(
    const float* __restrict__ h,        // [B,16,128]
    const float* __restrict__ pol,      // [B,16,8]
    const float* __restrict__ act,      // [B,16,8]
    float* __restrict__ ws,
    float* __restrict__ out_w)          // [B*16,16,1]
{
  const int b = blockIdx.x;
  const int tid = threadIdx.x;
  const float* v = ws + WS_V;

  __shared__ float a_src_sm[16];
  __shared__ float a_dst_sm[16];
  __shared__ float w_sm[256];
  __shared__ float pol_sm[128];
  __shared__ float act_sm[128];

  if (tid < 128) {
    pol_sm[tid] = pol[(size_t)b * 128 + tid];
    act_sm[tid] = act[(size_t)b * 128 + tid];
  }

  // phase 1: a_src/a_dst (16 lanes per row, 8 elems per lane)
  {
    const int l = tid & 15;
    const f32x4* hp = (const f32x4*)(h + (size_t)b * (N_SZ * IN_DIM));
    const f32x4 h0 = __builtin_nontemporal_load(&hp[tid * 2]);
    const f32x4 h1 = __builtin_nontemporal_load(&hp[tid * 2 + 1]);
    const f32x4* vs = (const f32x4*)v;
    const f32x4* vd = (const f32x4*)(v + IN_DIM);
    const f32x4 s0 = vs[l * 2], s1 = vs[l * 2 + 1];
    const f32x4 d0 = vd[l * 2], d1 = vd[l * 2 + 1];
    float s = h0.x * s0.x + h0.y * s0.y + h0.z * s0.z + h0.w * s0.w
            + h1.x * s1.x + h1.y * s1.y + h1.z * s1.z + h1.w * s1.w;
    float d = h0.x * d0.x + h0.y * d0.y + h0.z * d0.z + h0.w * d0.w
            + h1.x * d1.x + h1.y * d1.y + h1.z * d1.z + h1.w * d1.w;
    for (int m = 8; m >= 1; m >>= 1) {
      s += __shfl_xor(s, m, 16);
      d += __shfl_xor(d, m, 16);
    }
    if (l == 0) {
      a_src_sm[tid >> 4] = s;
      a_dst_sm[tid >> 4] = d;
    }
  }
  __syncthreads();

  // persist a_src/a_dst for the streaming kernel
  if (tid < 16)       ws[WS_ASRC + b * 16 + tid] = a_src_sm[tid];
  else if (tid < 32)  ws[WS_ADST + b * 16 + (tid - 16)] = a_dst_sm[tid - 16];

  // phase 2: w[i][j]
  {
    float e = a_src_sm[tid & 15] + a_dst_sm[tid >> 4];
    e = (e >= 0.f) ? e : 0.01f * e;
    const float wv = 1.f / (1.f + expf(-e));
    w_sm[tid] = wv;
    out_w[(size_t)b * 256 + tid] = wv;
  }
  __syncthreads();

  // phase 3a: sum_z[i][a] -> ws
  if (tid < 128) {
    const int i = tid >> 3, a = tid & 7;
    float s = 0.f;
    #pragma unroll
    for (int j = 0; j < N_SZ; ++j) {
      const float wv = w_sm[i * 16 + j];
      s += wv * act_sm[j * 8 + a] + (1.f - wv) * pol_sm[j * 8 + a];
    }
    ws[WS_SUMZ + b * 128 + tid] = s;
  }
}

// ---------------------------------------------------------------------------
// Kernel 2b (new path): fill-shaped dense-front writer of out0.
// Grid-stride over all 35,651,584 float4s; zero LDS, zero barriers.
// Head lanes copy obs (cached, 16x reuse); tail lanes recompute the z-tail.
// Every store instruction: 64 lanes x 16 B contiguous = full lines.
// ---------------------------------------------------------------------------
__global__ __launch_bounds__(256) void gat_stream_full(
    const float* __restrict__ obs,      // [B*16,128]
    const float* __restrict__ pol,      // [B,16,8]
    const float* __restrict__ act,      // [B,16,8]
    const float* __restrict__ ws,
    float* __restrict__ out_obs)        // [B*16,16,136]
{
  const float* __restrict__ asrc = ws + WS_ASRC;
  const float* __restrict__ adst = ws + WS_ADST;
  const f32x4* __restrict__ sumz4 = (const f32x4*)(ws + WS_SUMZ);
  const f32x4* __restrict__ obs4 = (const f32x4*)obs;
  const f32x4* __restrict__ pol4 = (const f32x4*)pol;
  const f32x4* __restrict__ act4 = (const f32x4*)act;

  const unsigned total = B_SZ * 256u * 34u;            // 35,651,584
  const unsigned stride = gridDim.x * blockDim.x;      // 524,288 -> 68 iters
  for (unsigned idx = blockIdx.x * blockDim.x + threadIdx.x;
       idx < total; idx += stride) {
    const unsigned r  = idx / 34u;         // magic-mul div
    const unsigned d4 = idx - r * 34u;
    const unsigned bk = ((r >> 8) << 4) | (r & 15u);        // b*16 + k
    f32x4 val;
    if (d4 < 32u) {
      val = obs4[(size_t)bk * 32 + d4];
    } else {
      const unsigned t  = d4 - 32u;                         // 0 or 1
      const unsigned bi = ((r >> 8) << 4) | ((r >> 4) & 15u); // b*16 + i
      float e = asrc[bk] + adst[bi];
      e = (e >= 0.f) ? e : 0.01f * e;
      const float wv = 1.f / (1.f + expf(-e));
      const f32x4 pv = pol4[bk * 2 + t];
      const f32x4 av = act4[bk * 2 + t];
      const f32x4 sv = sumz4[bi * 2 + t];
      val = (sv - (wv * av + (1.f - wv) * pv) + pv) * 0.0625f;
    }
    __builtin_nontemporal_store(val, (f32x4*)out_obs + idx);
  }
}

// ---------------------------------------------------------------------------
// Fallback (old R9 path, proven 138 us) if ws is too small for the new path.
// ---------------------------------------------------------------------------
__global__ __launch_bounds__(256) void gat_main_old(
    const float* __restrict__ h, const float* __restrict__ pol,
    const float* __restrict__ act, const float* __restrict__ obs,
    const float* __restrict__ v, float* __restrict__ out_obs,
    float* __restrict__ out_w)
{
  const int b = ((blockIdx.x & 7) << 9) | (blockIdx.x >> 3);
  const int tid = threadIdx.x;
  __shared__ float a_src_sm[16];
  __shared__ float a_dst_sm[16];
  __shared__ float w_sm[256];
  __shared__ float pol_sm[128];
  __shared__ float act_sm[128];
  __shared__ float sumz_sm[128];
  __shared__ float outz_sm[2048];
  __shared__ float obs_sm[2048];
  {
    const f32x4* op = (const f32x4*)(obs + (size_t)b * (N_SZ * D_OBS));
    f32x4* od = (f32x4*)obs_sm;
    od[tid]       = __builtin_nontemporal_load(&op[tid]);
    od[tid + 256] = __builtin_nontemporal_load(&op[tid + 256]);
  }
  if (tid < 128) {
    pol_sm[tid] = pol[(size_t)b * 128 + tid];
    act_sm[tid] = act[(size_t)b * 128 + tid];
  }
  {
    const int l = tid & 15;
    const f32x4* hp = (const f32x4*)(h + (size_t)b * (N_SZ * IN_DIM));
    const f32x4 h0 = __builtin_nontemporal_load(&hp[tid * 2]);
    const f32x4 h1 = __builtin_nontemporal_load(&hp[tid * 2 + 1]);
    const f32x4* vs = (const f32x4*)v;
    const f32x4* vd = (const f32x4*)(v + IN_DIM);
    const f32x4 s0 = vs[l * 2], s1 = vs[l * 2 + 1];
    const f32x4 d0 = vd[l * 2], d1 = vd[l * 2 + 1];
    float s = h0.x * s0.x + h0.y * s0.y + h0.z * s0.z + h0.w * s0.w
            + h1.x * s1.x + h1.y * s1.y + h1.z * s1.z + h1.w * s1.w;
    float d = h0.x * d0.x + h0.y * d0.y + h0.z * d0.z + h0.w * d0.w
            + h1.x * d1.x + h1.y * d1.y + h1.z * d1.z + h1.w * d1.w;
    for (int m = 8; m >= 1; m >>= 1) {
      s += __shfl_xor(s, m, 16);
      d += __shfl_xor(d, m, 16);
    }
    if (l == 0) { a_src_sm[tid >> 4] = s; a_dst_sm[tid >> 4] = d; }
  }
  __syncthreads();
  {
    float e = a_src_sm[tid & 15] + a_dst_sm[tid >> 4];
    e = (e >= 0.f) ? e : 0.01f * e;
    const float wv = 1.f / (1.f + expf(-e));
    w_sm[tid] = wv;
    out_w[(size_t)b * 256 + tid] = wv;
  }
  __syncthreads();
  if (tid < 128) {
    const int i = tid >> 3, a = tid & 7;
    float s = 0.f;
    #pragma unroll
    for (int j = 0; j < N_SZ; ++j) {
      const float wv = w_sm[i * 16 + j];
      s += wv * act_sm[j * 8 + a] + (1.f - wv) * pol_sm[j * 8 + a];
    }
    sumz_sm[tid] = s;
  }
  __syncthreads();
  {
    const int i = tid >> 4, k = tid & 15;
    const float wv = w_sm[tid];
    #pragma unroll
    for (int a = 0; a < A_SZ; ++a) {
      const float zg = wv * act_sm[k * 8 + a] + (1.f - wv) * pol_sm[k * 8 + a];
      outz_sm[tid * 8 + a] =
          (sumz_sm[i * 8 + a] - zg + pol_sm[k * 8 + a]) * 0.0625f;
    }
  }
  __syncthreads();
  float* ob = out_obs + (size_t)b * (256 * ROW_OUT);
  const f32x4* obs4 = (const f32x4*)obs_sm;
  {
    int r  = tid / 34;
    int d4 = tid - r * 34;
    #pragma unroll 2
    for (int idx = tid; idx < 256 * 34; idx += 256) {
      f32x4 o4;
      if (d4 < 32) {
        o4 = obs4[(r & 15) * 32 + d4];
      } else {
        o4 = *(const f32x4*)(outz_sm + r * 8 + (d4 - 32) * 4);
      }
      *(f32x4*)(ob + (size_t)idx * 4) = o4;
      r += 7; d4 += 18;
      if (d4 >= 34) { d4 -= 34; ++r; }
    }
  }
}

// ---------------------------------------------------------------------------
extern "C" void kernel_launch(void* const* d_in, const int* in_sizes, int n_in,
                              void* d_out, int out_size, void* d_ws, size_t ws_size,
                              hipStream_t stream) {
  const float* h      = (const float*)d_in[0];
  const float* pol    = (const float*)d_in[1];
  const float* act    = (const float*)d_in[2];
  const float* obs    = (const float*)d_in[3];
  const float* W_fc   = (const float*)d_in[4];
  const float* W_attn = (const float*)d_in[5];

  float* out = (float*)d_out;
  float* out_w = out + (size_t)B_SZ * N_SZ * N_SZ * ROW_OUT;  // 142,606,336
  float* ws = (float*)d_ws;

  prep_v<<<1, 1024, 0, stream>>>(W_fc, W_attn, ws + WS_V);

  if (ws_size >= (size_t)WS_FLOATS * sizeof(float)) {
    gat_compute<<<B_SZ, 256, 0, stream>>>(h, pol, act, ws, out_w);
    gat_stream_full<<<2048, 256, 0, stream>>>(obs, pol, act, ws, out);
  } else {
    gat_main_old<<<B_SZ, 256, 0, stream>>>(h, pol, act, obs, ws + WS_V, out, out_w);
  }
}

// Round 11
// 142.285 us; speedup vs baseline: 1.0746x; 1.0746x over previous
//
#include <hip/hip_runtime.h>
#include <math.h>

// Sizes from the reference
#define B_SZ 4096
#define N_SZ 16
#define A_SZ 8
#define IN_DIM 128
#define OUT_DIM 128
#define D_OBS 128
#define ROW_OUT 136              // floats per output row = 34 float4

typedef float f32x4 __attribute__((ext_vector_type(4)));

// ---------------------------------------------------------------------------
// Kernel 1: fold W_attn into W_fc.
//   v_src[i] = sum_o W_fc[o,i]*W_attn[o]; v_dst[i] = sum_o W_fc[o,i]*W_attn[128+o]
// ---------------------------------------------------------------------------
__global__ __launch_bounds__(1024) void prep_v(const float* __restrict__ W_fc,
                                               const float* __restrict__ W_attn,
                                               float* __restrict__ v) {
  __shared__ float part[8][2][128];
  const int i = threadIdx.x & 127;
  const int seg = threadIdx.x >> 7;
  float s = 0.f, d = 0.f;
  #pragma unroll
  for (int oo = 0; oo < 16; ++oo) {
    const int o = seg * 16 + oo;
    const float w = W_fc[o * IN_DIM + i];
    s += w * W_attn[o];
    d += w * W_attn[OUT_DIM + o];
  }
  part[seg][0][i] = s;
  part[seg][1][i] = d;
  __syncthreads();
  if (seg == 0) {
    float ss = 0.f, dd = 0.f;
    #pragma unroll
    for (int t = 0; t < 8; ++t) { ss += part[t][0][i]; dd += part[t][1][i]; }
    v[i] = ss;
    v[IN_DIM + i] = dd;
  }
}

// ---------------------------------------------------------------------------
// Kernel 2: one block per batch element (R9 chassis). Phase 4 rewritten with
// wave-static pow2 geometry: no division, no data-dependent branch; each wave
// writes 2 full rows (heads) then immediately their 32B z-tails (lanes 0-3),
// so tail stores merge with head lines while L2-dirty (full-line evictions).
// ---------------------------------------------------------------------------
__global__ __launch_bounds__(256) void gat_main(
    const float* __restrict__ h,        // [B,16,128]
    const float* __restrict__ pol,      // [B,16,8]
    const float* __restrict__ act,      // [B,16,8]
    const float* __restrict__ obs,      // [B*16,128]
    const float* __restrict__ v,        // [256] (v_src | v_dst)
    float* __restrict__ out_obs,        // [B*16,16,136]
    float* __restrict__ out_w)          // [B*16,16,1]
{
  // XCD-bijective swizzle: XCD x (= bid%8) gets contiguous b-slab
  const int b = ((blockIdx.x & 7) << 9) | (blockIdx.x >> 3);
  const int tid = threadIdx.x;

  __shared__ float a_src_sm[16];
  __shared__ float a_dst_sm[16];
  __shared__ float w_sm[256];        // [i][j]
  __shared__ float pol_sm[128];      // [j][a]
  __shared__ float act_sm[128];
  __shared__ float sumz_sm[128];     // [i][a]
  __shared__ float outz_sm[2048];    // [i][k][a]
  __shared__ float obs_sm[2048];     // [k][d]

  // --- stage obs tile (16x128 = 512 x 16B), streaming loads ---
  {
    const f32x4* op = (const f32x4*)(obs + (size_t)b * (N_SZ * D_OBS));
    f32x4* od = (f32x4*)obs_sm;
    od[tid]       = __builtin_nontemporal_load(&op[tid]);
    od[tid + 256] = __builtin_nontemporal_load(&op[tid + 256]);
  }
  // --- stage policies / actions ---
  if (tid < 128) {
    pol_sm[tid] = __builtin_nontemporal_load(&pol[(size_t)b * (N_SZ * A_SZ) + tid]);
    act_sm[tid] = __builtin_nontemporal_load(&act[(size_t)b * (N_SZ * A_SZ) + tid]);
  }

  // --- phase 1: a_src/a_dst. 16 lanes per row, 8 elems per lane. ---
  {
    const int l = tid & 15;
    const f32x4* hp = (const f32x4*)(h + (size_t)b * (N_SZ * IN_DIM));
    const f32x4 h0 = __builtin_nontemporal_load(&hp[tid * 2]);
    const f32x4 h1 = __builtin_nontemporal_load(&hp[tid * 2 + 1]);
    const f32x4* vs = (const f32x4*)v;
    const f32x4* vd = (const f32x4*)(v + IN_DIM);
    const f32x4 s0 = vs[l * 2], s1 = vs[l * 2 + 1];
    const f32x4 d0 = vd[l * 2], d1 = vd[l * 2 + 1];
    float s = h0.x * s0.x + h0.y * s0.y + h0.z * s0.z + h0.w * s0.w
            + h1.x * s1.x + h1.y * s1.y + h1.z * s1.z + h1.w * s1.w;
    float d = h0.x * d0.x + h0.y * d0.y + h0.z * d0.z + h0.w * d0.w
            + h1.x * d1.x + h1.y * d1.y + h1.z * d1.z + h1.w * d1.w;
    for (int m = 8; m >= 1; m >>= 1) {
      s += __shfl_xor(s, m, 16);
      d += __shfl_xor(d, m, 16);
    }
    if (l == 0) {
      a_src_sm[tid >> 4] = s;
      a_dst_sm[tid >> 4] = d;
    }
  }
  __syncthreads();

  // --- phase 2: w[i][j] = sigmoid(leaky_relu(a_src[j] + a_dst[i], 0.01)) ---
  {
    float e = a_src_sm[tid & 15] + a_dst_sm[tid >> 4];
    e = (e >= 0.f) ? e : 0.01f * e;
    const float wv = 1.f / (1.f + expf(-e));
    w_sm[tid] = wv;
    out_w[(size_t)b * 256 + tid] = wv;   // output 1, coalesced, cached store
  }
  __syncthreads();

  // --- phase 3a: sum_z[i][a] ---
  if (tid < 128) {
    const int i = tid >> 3, a = tid & 7;
    float s = 0.f;
    #pragma unroll
    for (int j = 0; j < N_SZ; ++j) {
      const float wv = w_sm[i * 16 + j];
      s += wv * act_sm[j * 8 + a] + (1.f - wv) * pol_sm[j * 8 + a];
    }
    sumz_sm[tid] = s;
  }
  __syncthreads();

  // --- phase 3b: out_z[i][k][a] = (sum_z[i][a] - zg[i][k][a] + pol[k][a])/16 ---
  {
    const int i = tid >> 4, k = tid & 15;
    const float wv = w_sm[tid];   // w[i][k]
    #pragma unroll
    for (int a = 0; a < A_SZ; ++a) {
      const float zg = wv * act_sm[k * 8 + a] + (1.f - wv) * pol_sm[k * 8 + a];
      outz_sm[tid * 8 + a] =
          (sumz_sm[i * 8 + a] - zg + pol_sm[k * 8 + a]) * 0.0625f;
    }
  }
  __syncthreads();

  // --- phase 4: wave-static writer. Per iteration, each wave writes 2 full
  // rows: lanes 0-31 -> row r0 chunks 0-31, lanes 32-63 -> row r0+1; then
  // lanes 0-3 store the four 16B z-tails of those rows (line still L2-dirty
  // from the head stores -> full-line eviction). No div, no branch on data.
  {
    float* ob = out_obs + (size_t)b * (256 * ROW_OUT);
    const f32x4* obs4 = (const f32x4*)obs_sm;
    const int wave = tid >> 6;
    const int lane = tid & 63;
    const int half = lane >> 5;          // 0: row r0, 1: row r0+1
    const int c    = lane & 31;          // float4 column within head
    const int rt   = (lane >> 1) & 1;    // tail row select for lanes 0-3
    const int tt   = lane & 1;           // tail slot select for lanes 0-3

    #pragma unroll 8
    for (int it = 0; it < 32; ++it) {
      const int r0 = it * 8 + wave * 2;
      const int r  = r0 + half;
      // head: 2 x 512B contiguous runs per wave instruction
      const f32x4 o4 = obs4[(r & 15) * 32 + c];
      *(f32x4*)(ob + (size_t)r * ROW_OUT + c * 4) = o4;
      // tails: 4 lanes, 4 x 16B, same rows as the heads just stored
      if (lane < 4) {
        const int rr = r0 + rt;
        const f32x4 z4 = *(const f32x4*)(outz_sm + rr * 8 + tt * 4);
        *(f32x4*)(ob + (size_t)rr * ROW_OUT + D_OBS + tt * 4) = z4;
      }
    }
  }
}

// ---------------------------------------------------------------------------
extern "C" void kernel_launch(void* const* d_in, const int* in_sizes, int n_in,
                              void* d_out, int out_size, void* d_ws, size_t ws_size,
                              hipStream_t stream) {
  const float* h      = (const float*)d_in[0];
  const float* pol    = (const float*)d_in[1];
  const float* act    = (const float*)d_in[2];
  const float* obs    = (const float*)d_in[3];
  const float* W_fc   = (const float*)d_in[4];
  const float* W_attn = (const float*)d_in[5];

  float* out = (float*)d_out;
  float* out_w = out + (size_t)B_SZ * N_SZ * N_SZ * ROW_OUT;  // 142,606,336
  float* v = (float*)d_ws;  // 256 floats

  prep_v<<<1, 1024, 0, stream>>>(W_fc, W_attn, v);
  gat_main<<<B_SZ, 256, 0, stream>>>(h, pol, act, obs, v, out, out_w);
}